// Round 4
// baseline (2078.228 us; speedup 1.0000x reference)
//
#include <hip/hip_runtime.h>
#include <math.h>

#define T_LEN 8192
#define NUM_CH 64
#define HID 256
#define NUM_CLS 40
#define NUM_PROP 1024
#define NUM_PROP_AFTER 256
#define PROP_LEN 128
#define MS 4                     // sequences per block
#define NBLK (NUM_PROP_AFTER / MS)   // 64 blocks
#define NCHUNK 40                // 40 chunks x 8 halves = K=320 (256 h + 64 x)
#define WRING 4                  // W prefetch ring depth; NCHUNK % WRING == 0 !

typedef _Float16 h2_t __attribute__((ext_vector_type(2)));
union U32H2 { unsigned int u; h2_t h; };
union HU16 { _Float16 h; unsigned short u; };

#if defined(__has_builtin)
#if __has_builtin(__builtin_amdgcn_fdot2)
#define HAS_FDOT2 1
#endif
#endif

__device__ __forceinline__ float dot2f(unsigned int wa, unsigned int hb, float acc) {
    U32H2 a, b;
    a.u = wa;
    b.u = hb;
#ifdef HAS_FDOT2
    return __builtin_amdgcn_fdot2(a.h, b.h, acc, false);
#else
    return acc + (float)a.h[0] * (float)b.h[0] + (float)a.h[1] * (float)b.h[1];
#endif
}

__device__ __forceinline__ float dot8f(const uint4& w, const uint4& h, float acc) {
    acc = dot2f(w.x, h.x, acc);
    acc = dot2f(w.y, h.y, acc);
    acc = dot2f(w.z, h.z, acc);
    acc = dot2f(w.w, h.w, acc);
    return acc;
}

__device__ __forceinline__ float fsigmoid(float x) { return 1.0f / (1.0f + __expf(-x)); }
__device__ __forceinline__ float ftanh(float x) {
    float e = __expf(-2.0f * fabsf(x));
    float t = (1.0f - e) / (1.0f + e);
    return copysignf(t, x);
}

// ---------------------------------------------------------------------------
// Pack W into f16, K-major, gate-split layout:
//   WQ[((c*4 + gate)*256 + u)*8 + j],  row r = gate*256+u, k = c*8+j
//   k < 256 -> W_hh[r][k], else W_ih[r][k-256]
// ---------------------------------------------------------------------------
__global__ __launch_bounds__(256) void pack_w(const float* __restrict__ W_ih,
                                              const float* __restrict__ W_hh,
                                              unsigned short* __restrict__ WQ) {
    int e = blockIdx.x * 256 + threadIdx.x;  // 0 .. 327679
    int j = e & 7;
    int u = (e >> 3) & 255;
    int g = (e >> 11) & 3;
    int c = e >> 13;
    int r = g * 256 + u;
    int k = c * 8 + j;
    float v = (k < HID) ? W_hh[r * HID + k] : W_ih[r * NUM_CH + (k - HID)];
    HU16 hv;
    hv.h = (_Float16)v;
    WQ[e] = hv.u;
}

// ---------------------------------------------------------------------------
// NMS: rank by score (float4 reads), chunk-serial greedy resolution (wave 0)
// + parallel apply (float2 interval reads).
// ---------------------------------------------------------------------------
__global__ __launch_bounds__(1024) void nms_kernel(const float* __restrict__ prop,
                                                   int* __restrict__ t0_out) {
    __shared__ __align__(16) float s_sc[NUM_PROP];
    __shared__ __align__(8) float2 sse[NUM_PROP];  // (start, end) by rank
    __shared__ unsigned char sup[NUM_PROP];
    __shared__ unsigned long long cmask[16];

    const int tid = threadIdx.x;
    float ps = prop[tid * 3 + 0];
    float pe = prop[tid * 3 + 1];
    float pc = prop[tid * 3 + 2];
    s_sc[tid] = pc;
    sup[tid] = 0;
    __syncthreads();

    // stable rank in descending-score order
    int r = 0;
    const float4* sc4 = (const float4*)s_sc;
    for (int q = 0; q < NUM_PROP / 4; ++q) {
        float4 v = sc4[q];
        int j = q * 4;
        r += (v.x > pc) || (v.x == pc && (j + 0) < tid);
        r += (v.y > pc) || (v.y == pc && (j + 1) < tid);
        r += (v.z > pc) || (v.z == pc && (j + 2) < tid);
        r += (v.w > pc) || (v.w == pc && (j + 3) < tid);
    }
    sse[r] = make_float2(ps, pe);
    __syncthreads();

    const float my_s = sse[tid].x;
    const float my_e = sse[tid].y;
    const float my_len = my_e - my_s;
    bool mysup = false;

    for (int ci = 0; ci < 16; ++ci) {
        if (tid < 64) {  // wave 0 resolves intra-chunk suppression serially
            int i = ci * 64 + tid;
            float2 ie2 = sse[i];
            float is_ = ie2.x, ie_ = ie2.y;
            unsigned long long m = __ballot(sup[i] != 0);
            for (int l = 0; l < 64; ++l) {
                if (!((m >> l) & 1)) {  // uniform: m is lane-uniform
                    float ls = __shfl(is_, l);
                    float le = __shfl(ie_, l);
                    float inter = fmaxf(fminf(le, ie_) - fmaxf(ls, is_), 0.0f);
                    float uni = (le - ls) + (ie_ - is_) - inter;
                    float iou = inter / fmaxf(uni, 1e-6f);
                    unsigned long long nb = __ballot((tid > l) && (iou > 0.5f));
                    m |= nb;
                }
            }
            sup[i] = (unsigned char)((m >> tid) & 1);
            if (tid == 0) cmask[ci] = ~m;
        }
        __syncthreads();
        unsigned long long am = cmask[ci];
        for (int l = 0; l < 64; ++l) {
            if ((am >> l) & 1) {  // uniform
                int i = ci * 64 + l;
                if (tid > i && !mysup) {
                    float2 ie2 = sse[i];
                    float inter = fmaxf(fminf(ie2.y, my_e) - fmaxf(ie2.x, my_s), 0.0f);
                    float uni = (ie2.y - ie2.x) + my_len - inter;
                    if (inter / fmaxf(uni, 1e-6f) > 0.5f) mysup = true;
                }
            }
        }
        sup[tid] = mysup ? 1 : 0;
        __syncthreads();
    }

    // stable partition: kept (by rank) then suppressed (by rank)
    int myc = tid >> 6;
    unsigned long long mybit = 1ull << (tid & 63);
    int kb = 0, kt = 0;
    for (int c2 = 0; c2 < 16; ++c2) {
        int p = __popcll(cmask[c2]);
        kt += p;
        if (c2 < myc) kb += p;
    }
    kb += __popcll(cmask[myc] & (mybit - 1));
    int slot = (cmask[myc] & mybit) ? kb : (kt + (tid - kb));
    if (slot < NUM_PROP_AFTER) {
        int t0 = (int)rintf(my_s);
        t0 = max(0, min(t0, T_LEN - PROP_LEN));
        t0_out[slot] = t0;
    }
}

// ---------------------------------------------------------------------------
// LSTM: 64 blocks x 256 threads. Thread t owns unit t's i,f,g,o rows (R=4)
// for MS=4 sequences -> epilogue is register-local, ONE barrier per step.
// W streamed f16 from L2 with a depth-4 ring prefetch (40 % 4 == 0, so the
// wrap phase is aligned across steps -- depth 3 was the round-3 bug).
// h/x live as f16 in LDS (broadcast reads).
// ---------------------------------------------------------------------------
__global__ __launch_bounds__(256) void lstm_kernel(
    const float* __restrict__ data, const int* __restrict__ t0s,
    const unsigned short* __restrict__ WQ,
    const float* __restrict__ b_ih, const float* __restrict__ b_hh,
    const float* __restrict__ W_cls, const float* __restrict__ b_cls,
    const float* __restrict__ W_bbox, const float* __restrict__ b_bbox,
    float* __restrict__ out) {
    __shared__ __align__(16) _Float16 hx[2][NCHUNK][MS][8];

    const int tid = threadIdx.x;  // hidden unit
    const int sbase = blockIdx.x * MS;

    float bias[4];
#pragma unroll
    for (int g = 0; g < 4; ++g) bias[g] = b_ih[g * 256 + tid] + b_hh[g * 256 + tid];

    int t0[MS];
#pragma unroll
    for (int s = 0; s < MS; ++s) t0[s] = t0s[sbase + s];

    // init hx[0]: h = 0 (chunks 0..31), x(0) (chunks 32..39)
    if (tid < 128) ((uint4*)&hx[0][0][0][0])[tid] = make_uint4(0, 0, 0, 0);
    const int xs = tid >> 6, xch = tid & 63;
    {
        HU16 hv;
        hv.h = (_Float16)data[t0[xs] * NUM_CH + xch];
        hx[0][32 + (xch >> 3)][xs][xch & 7] = hv.h;
    }
    float cst[MS] = {0.0f, 0.0f, 0.0f, 0.0f};
    __syncthreads();

    const uint4* wq4 = (const uint4*)WQ;

    // W ring prefetch: wbuf slot c%4 holds chunk c; prefetch (c+4)%40 into the
    // slot being freed. Since NCHUNK % WRING == 0, the end-of-step wrap leaves
    // chunks 0..3 in slots 0..3 exactly as the next step expects.
    uint4 wbuf[WRING][4];
#pragma unroll
    for (int p = 0; p < WRING; ++p)
#pragma unroll
        for (int g = 0; g < 4; ++g) wbuf[p][g] = wq4[((p * 4 + g) << 8) | tid];

#pragma unroll 2
    for (int t = 0; t < PROP_LEN; ++t) {
        const int cur = t & 1, nxt = cur ^ 1;

        // issue next x load early (consumed after the chunk loop)
        float xnext = 0.0f;
        if (t < PROP_LEN - 1) xnext = data[(t0[xs] + t + 1) * NUM_CH + xch];

        float acc[4][MS];
#pragma unroll
        for (int g = 0; g < 4; ++g)
#pragma unroll
            for (int s = 0; s < MS; ++s) acc[g][s] = bias[g];

        uint4 hbuf[2][MS];
#pragma unroll
        for (int s = 0; s < MS; ++s) hbuf[0][s] = *(const uint4*)&hx[cur][0][s][0];

#pragma unroll
        for (int c = 0; c < NCHUNK; ++c) {
            uint4 w0 = wbuf[c % WRING][0], w1 = wbuf[c % WRING][1];
            uint4 w2 = wbuf[c % WRING][2], w3 = wbuf[c % WRING][3];
            // prefetch chunk (c+WRING) mod 40 into the freed slot
            {
                const int pc_ = (c + WRING < NCHUNK) ? (c + WRING) : (c + WRING - NCHUNK);
#pragma unroll
                for (int g = 0; g < 4; ++g)
                    wbuf[c % WRING][g] = wq4[((pc_ * 4 + g) << 8) | tid];
            }
            uint4 hh[MS];
#pragma unroll
            for (int s = 0; s < MS; ++s) hh[s] = hbuf[c & 1][s];
            if (c + 1 < NCHUNK) {
#pragma unroll
                for (int s = 0; s < MS; ++s)
                    hbuf[(c + 1) & 1][s] = *(const uint4*)&hx[cur][c + 1][s][0];
            }
#pragma unroll
            for (int s = 0; s < MS; ++s) {
                acc[0][s] = dot8f(w0, hh[s], acc[0][s]);
                acc[1][s] = dot8f(w1, hh[s], acc[1][s]);
                acc[2][s] = dot8f(w2, hh[s], acc[2][s]);
                acc[3][s] = dot8f(w3, hh[s], acc[3][s]);
            }
        }

        // register-local epilogue: thread owns i,f,g,o of unit `tid`
#pragma unroll
        for (int s = 0; s < MS; ++s) {
            float gi = fsigmoid(acc[0][s]);
            float gf = fsigmoid(acc[1][s]);
            float gg = ftanh(acc[2][s]);
            float go = fsigmoid(acc[3][s]);
            cst[s] = gf * cst[s] + gi * gg;
            float h = go * ftanh(cst[s]);
            HU16 hv;
            hv.h = (_Float16)h;
            hx[nxt][tid >> 3][s][tid & 7] = hv.h;
        }
        if (t < PROP_LEN - 1) {
            HU16 hv;
            hv.h = (_Float16)xnext;
            hx[nxt][32 + (xch >> 3)][xs][xch & 7] = hv.h;
        }
        __syncthreads();
    }

    // final h is in hx[0] (t=127: nxt=0). Heads: 480 jobs over 256 threads.
#pragma unroll
    for (int rep = 0; rep < 2; ++rep) {
        int o = rep * 256 + tid;
        if (o < MS * 120) {
            int s = o / 120;
            int m = o % 120;
            const float* Wrow;
            float acc;
            int oidx;
            if (m < NUM_CLS) {
                Wrow = W_cls + m * HID;
                acc = b_cls[m];
                oidx = (sbase + s) * NUM_CLS + m;
            } else {
                int mb = m - NUM_CLS;
                Wrow = W_bbox + mb * HID;
                acc = b_bbox[mb];
                oidx = NUM_PROP_AFTER * NUM_CLS + (sbase + s) * 2 * NUM_CLS + mb;
            }
            const float4* w4 = (const float4*)Wrow;
            for (int c = 0; c < 32; ++c) {
                uint4 hv = *(const uint4*)&hx[0][c][s][0];
                U32H2 p0, p1, p2, p3;
                p0.u = hv.x; p1.u = hv.y; p2.u = hv.z; p3.u = hv.w;
                float4 wa = w4[2 * c], wb = w4[2 * c + 1];
                acc += (float)p0.h[0] * wa.x + (float)p0.h[1] * wa.y +
                       (float)p1.h[0] * wa.z + (float)p1.h[1] * wa.w +
                       (float)p2.h[0] * wb.x + (float)p2.h[1] * wb.y +
                       (float)p3.h[0] * wb.z + (float)p3.h[1] * wb.w;
            }
            out[oidx] = acc;
        }
    }
}

extern "C" void kernel_launch(void* const* d_in, const int* in_sizes, int n_in,
                              void* d_out, int out_size, void* d_ws,
                              size_t ws_size, hipStream_t stream) {
    const float* data = (const float*)d_in[0];     // [8192, 64]
    const float* prop = (const float*)d_in[1];     // [1024, 3]
    const float* W_ih = (const float*)d_in[2];     // [1024, 64]
    const float* W_hh = (const float*)d_in[3];     // [1024, 256]
    const float* b_ih = (const float*)d_in[4];     // [1024]
    const float* b_hh = (const float*)d_in[5];     // [1024]
    const float* W_cls = (const float*)d_in[6];    // [40, 256]
    const float* b_cls = (const float*)d_in[7];    // [40]
    const float* W_bbox = (const float*)d_in[8];   // [80, 256]
    const float* b_bbox = (const float*)d_in[9];   // [80]
    float* out = (float*)d_out;

    int* t0s = (int*)d_ws;                                       // 1 KB
    unsigned short* WQ = (unsigned short*)((char*)d_ws + 1024);  // 640 KB f16

    pack_w<<<1280, 256, 0, stream>>>(W_ih, W_hh, WQ);
    nms_kernel<<<1, 1024, 0, stream>>>(prop, t0s);
    lstm_kernel<<<NBLK, 256, 0, stream>>>(data, t0s, WQ, b_ih, b_hh, W_cls,
                                          b_cls, W_bbox, b_bbox, out);
}

// Round 5
// 1414.967 us; speedup vs baseline: 1.4687x; 1.4687x over previous
//
#include <hip/hip_runtime.h>
#include <math.h>

#define T_LEN 8192
#define NUM_CH 64
#define HID 256
#define NUM_CLS 40
#define NUM_PROP 1024
#define NUM_PROP_AFTER 256
#define PROP_LEN 128
#define MS 4                         // sequences per block
#define NBLK (NUM_PROP_AFTER / MS)   // 64 blocks
#define NCHUNK 40                    // 40 chunks x 8 halves = K=320 (256 h + 64 x)
#define HCHUNK 20                    // chunks per half-block (K-split)
#define WRING 4                      // ring depth; HCHUNK % WRING == 0

typedef _Float16 h2_t __attribute__((ext_vector_type(2)));
union U32H2 { unsigned int u; h2_t h; };
union HU16 { _Float16 h; unsigned short u; };

#if defined(__has_builtin)
#if __has_builtin(__builtin_amdgcn_fdot2)
#define HAS_FDOT2 1
#endif
#endif

__device__ __forceinline__ float dot2f(unsigned int wa, unsigned int hb, float acc) {
    U32H2 a, b;
    a.u = wa;
    b.u = hb;
#ifdef HAS_FDOT2
    return __builtin_amdgcn_fdot2(a.h, b.h, acc, false);
#else
    return acc + (float)a.h[0] * (float)b.h[0] + (float)a.h[1] * (float)b.h[1];
#endif
}

__device__ __forceinline__ float dot8f(const uint4& w, const uint4& h, float acc) {
    acc = dot2f(w.x, h.x, acc);
    acc = dot2f(w.y, h.y, acc);
    acc = dot2f(w.z, h.z, acc);
    acc = dot2f(w.w, h.w, acc);
    return acc;
}

__device__ __forceinline__ float fsigmoid(float x) { return 1.0f / (1.0f + __expf(-x)); }
__device__ __forceinline__ float ftanh(float x) {
    float e = __expf(-2.0f * fabsf(x));
    float t = (1.0f - e) / (1.0f + e);
    return copysignf(t, x);
}

// ---------------------------------------------------------------------------
// Pack W into f16, K-major, gate-split layout:
//   WQ[((c*4 + gate)*256 + u)*8 + j],  row r = gate*256+u, k = c*8+j
//   k < 256 -> W_hh[r][k], else W_ih[r][k-256]
// ---------------------------------------------------------------------------
__global__ __launch_bounds__(256) void pack_w(const float* __restrict__ W_ih,
                                              const float* __restrict__ W_hh,
                                              unsigned short* __restrict__ WQ) {
    int e = blockIdx.x * 256 + threadIdx.x;  // 0 .. 327679
    int j = e & 7;
    int u = (e >> 3) & 255;
    int g = (e >> 11) & 3;
    int c = e >> 13;
    int r = g * 256 + u;
    int k = c * 8 + j;
    float v = (k < HID) ? W_hh[r * HID + k] : W_ih[r * NUM_CH + (k - HID)];
    HU16 hv;
    hv.h = (_Float16)v;
    WQ[e] = hv.u;
}

// ---------------------------------------------------------------------------
// NMS: rank by score (float4 reads), chunk-serial greedy resolution (wave 0)
// + parallel apply (float2 interval reads).
// ---------------------------------------------------------------------------
__global__ __launch_bounds__(1024) void nms_kernel(const float* __restrict__ prop,
                                                   int* __restrict__ t0_out) {
    __shared__ __align__(16) float s_sc[NUM_PROP];
    __shared__ __align__(8) float2 sse[NUM_PROP];  // (start, end) by rank
    __shared__ unsigned char sup[NUM_PROP];
    __shared__ unsigned long long cmask[16];

    const int tid = threadIdx.x;
    float ps = prop[tid * 3 + 0];
    float pe = prop[tid * 3 + 1];
    float pc = prop[tid * 3 + 2];
    s_sc[tid] = pc;
    sup[tid] = 0;
    __syncthreads();

    // stable rank in descending-score order
    int r = 0;
    const float4* sc4 = (const float4*)s_sc;
    for (int q = 0; q < NUM_PROP / 4; ++q) {
        float4 v = sc4[q];
        int j = q * 4;
        r += (v.x > pc) || (v.x == pc && (j + 0) < tid);
        r += (v.y > pc) || (v.y == pc && (j + 1) < tid);
        r += (v.z > pc) || (v.z == pc && (j + 2) < tid);
        r += (v.w > pc) || (v.w == pc && (j + 3) < tid);
    }
    sse[r] = make_float2(ps, pe);
    __syncthreads();

    const float my_s = sse[tid].x;
    const float my_e = sse[tid].y;
    const float my_len = my_e - my_s;
    bool mysup = false;

    for (int ci = 0; ci < 16; ++ci) {
        if (tid < 64) {  // wave 0 resolves intra-chunk suppression serially
            int i = ci * 64 + tid;
            float2 ie2 = sse[i];
            float is_ = ie2.x, ie_ = ie2.y;
            unsigned long long m = __ballot(sup[i] != 0);
            for (int l = 0; l < 64; ++l) {
                if (!((m >> l) & 1)) {  // uniform: m is lane-uniform
                    float ls = __shfl(is_, l);
                    float le = __shfl(ie_, l);
                    float inter = fmaxf(fminf(le, ie_) - fmaxf(ls, is_), 0.0f);
                    float uni = (le - ls) + (ie_ - is_) - inter;
                    float iou = inter / fmaxf(uni, 1e-6f);
                    unsigned long long nb = __ballot((tid > l) && (iou > 0.5f));
                    m |= nb;
                }
            }
            sup[i] = (unsigned char)((m >> tid) & 1);
            if (tid == 0) cmask[ci] = ~m;
        }
        __syncthreads();
        unsigned long long am = cmask[ci];
        for (int l = 0; l < 64; ++l) {
            if ((am >> l) & 1) {  // uniform
                int i = ci * 64 + l;
                if (tid > i && !mysup) {
                    float2 ie2 = sse[i];
                    float inter = fmaxf(fminf(ie2.y, my_e) - fmaxf(ie2.x, my_s), 0.0f);
                    float uni = (ie2.y - ie2.x) + my_len - inter;
                    if (inter / fmaxf(uni, 1e-6f) > 0.5f) mysup = true;
                }
            }
        }
        sup[tid] = mysup ? 1 : 0;
        __syncthreads();
    }

    // stable partition: kept (by rank) then suppressed (by rank)
    int myc = tid >> 6;
    unsigned long long mybit = 1ull << (tid & 63);
    int kb = 0, kt = 0;
    for (int c2 = 0; c2 < 16; ++c2) {
        int p = __popcll(cmask[c2]);
        kt += p;
        if (c2 < myc) kb += p;
    }
    kb += __popcll(cmask[myc] & (mybit - 1));
    int slot = (cmask[myc] & mybit) ? kb : (kt + (tid - kb));
    if (slot < NUM_PROP_AFTER) {
        int t0 = (int)rintf(my_s);
        t0 = max(0, min(t0, T_LEN - PROP_LEN));
        t0_out[slot] = t0;
    }
}

// ---------------------------------------------------------------------------
// LSTM: 64 blocks x 512 threads (8 waves/CU = 2 waves/SIMD for latency
// hiding).  K-split: half = tid>>8 handles 20 of 40 K-chunks for unit
// u = tid&255, all 4 gates, MS=4 sequences.  Half 1 dumps fp32 partials to
// LDS; half 0 combines + runs the gate epilogue (register-local c-state);
// half 1 concurrently writes the next x into the h/x double buffer.
// W streamed f16 from L2, depth-4 ring (20 % 4 == 0: wrap phase-aligned).
// ---------------------------------------------------------------------------
__global__ __launch_bounds__(512, 2) void lstm_kernel(
    const float* __restrict__ data, const int* __restrict__ t0s,
    const unsigned short* __restrict__ WQ,
    const float* __restrict__ b_ih, const float* __restrict__ b_hh,
    const float* __restrict__ W_cls, const float* __restrict__ b_cls,
    const float* __restrict__ W_bbox, const float* __restrict__ b_bbox,
    float* __restrict__ out) {
    __shared__ __align__(16) _Float16 hx[2][NCHUNK][MS][8];   // 5 KB
    __shared__ __align__(16) float pacc[HID][MS][4];          // 16 KB [u][s][gate]

    const int tid = threadIdx.x;
    const int half = tid >> 8;    // K-slice
    const int u = tid & 255;      // hidden unit
    const int c0 = half * HCHUNK; // first chunk of my K-slice
    const int sbase = blockIdx.x * MS;

    float bias[4];
#pragma unroll
    for (int g = 0; g < 4; ++g) bias[g] = b_ih[g * 256 + u] + b_hh[g * 256 + u];

    int t0[MS];
#pragma unroll
    for (int s = 0; s < MS; ++s) t0[s] = t0s[sbase + s];

    // init hx[0]: h = 0 (chunks 0..31) by first 128 threads; x(0) by half 1.
    if (tid < 128) ((uint4*)&hx[0][0][0][0])[tid] = make_uint4(0, 0, 0, 0);
    const int xs = u >> 6, xch = u & 63;  // half 1's x-loader role
    if (half == 1) {
        HU16 hv;
        hv.h = (_Float16)data[t0[xs] * NUM_CH + xch];
        hx[0][32 + (xch >> 3)][xs][xch & 7] = hv.h;
    }
    float cst[MS] = {0.0f, 0.0f, 0.0f, 0.0f};
    __syncthreads();

    const uint4* wq4 = (const uint4*)WQ;

    // W ring: slot (local chunk)%4 holds that chunk's 4 gate-rows.
    uint4 wbuf[WRING][4];
#pragma unroll
    for (int p = 0; p < WRING; ++p)
#pragma unroll
        for (int g = 0; g < 4; ++g) wbuf[p][g] = wq4[(((c0 + p) * 4 + g) << 8) | u];

    for (int t = 0; t < PROP_LEN; ++t) {
        const int cur = t & 1, nxt = cur ^ 1;

        // half 1 issues next x load early (consumed after the chunk loop)
        float xnext = 0.0f;
        if (half == 1 && t < PROP_LEN - 1)
            xnext = data[(t0[xs] + t + 1) * NUM_CH + xch];

        float acc[4][MS];
#pragma unroll
        for (int g = 0; g < 4; ++g)
#pragma unroll
            for (int s = 0; s < MS; ++s) acc[g][s] = 0.0f;

        uint4 hbuf[2][MS];
#pragma unroll
        for (int s = 0; s < MS; ++s) hbuf[0][s] = *(const uint4*)&hx[cur][c0][s][0];

#pragma unroll 4
        for (int c = 0; c < HCHUNK; ++c) {
            uint4 w0 = wbuf[c % WRING][0], w1 = wbuf[c % WRING][1];
            uint4 w2 = wbuf[c % WRING][2], w3 = wbuf[c % WRING][3];
            // prefetch local chunk (c+4)%20 into the freed slot (phase-aligned)
            {
                int pc_ = c + WRING;
                if (pc_ >= HCHUNK) pc_ -= HCHUNK;
#pragma unroll
                for (int g = 0; g < 4; ++g)
                    wbuf[c % WRING][g] = wq4[(((c0 + pc_) * 4 + g) << 8) | u];
            }
            uint4 hh[MS];
#pragma unroll
            for (int s = 0; s < MS; ++s) hh[s] = hbuf[c & 1][s];
            if (c + 1 < HCHUNK) {
#pragma unroll
                for (int s = 0; s < MS; ++s)
                    hbuf[(c + 1) & 1][s] = *(const uint4*)&hx[cur][c0 + c + 1][s][0];
            }
#pragma unroll
            for (int s = 0; s < MS; ++s) {
                acc[0][s] = dot8f(w0, hh[s], acc[0][s]);
                acc[1][s] = dot8f(w1, hh[s], acc[1][s]);
                acc[2][s] = dot8f(w2, hh[s], acc[2][s]);
                acc[3][s] = dot8f(w3, hh[s], acc[3][s]);
            }
        }

        if (half == 1) {
#pragma unroll
            for (int s = 0; s < MS; ++s)
                *(float4*)&pacc[u][s][0] =
                    make_float4(acc[0][s], acc[1][s], acc[2][s], acc[3][s]);
        }
        __syncthreads();

        if (half == 0) {
            // combine partials + gate epilogue (c-state register-local)
#pragma unroll
            for (int s = 0; s < MS; ++s) {
                float4 p = *(const float4*)&pacc[u][s][0];
                float gi = fsigmoid(acc[0][s] + p.x + bias[0]);
                float gf = fsigmoid(acc[1][s] + p.y + bias[1]);
                float gg = ftanh(acc[2][s] + p.z + bias[2]);
                float go = fsigmoid(acc[3][s] + p.w + bias[3]);
                cst[s] = gf * cst[s] + gi * gg;
                float h = go * ftanh(cst[s]);
                HU16 hv;
                hv.h = (_Float16)h;
                hx[nxt][u >> 3][s][u & 7] = hv.h;
            }
        } else if (t < PROP_LEN - 1) {
            HU16 hv;
            hv.h = (_Float16)xnext;
            hx[nxt][32 + (xch >> 3)][xs][xch & 7] = hv.h;
        }
        __syncthreads();
    }

    // final h is in hx[0] (t=127: nxt=0). Heads: 480 jobs, one per thread.
    if (tid < MS * 120) {
        int s = tid / 120;
        int m = tid % 120;
        const float* Wrow;
        float acc;
        int oidx;
        if (m < NUM_CLS) {
            Wrow = W_cls + m * HID;
            acc = b_cls[m];
            oidx = (sbase + s) * NUM_CLS + m;
        } else {
            int mb = m - NUM_CLS;
            Wrow = W_bbox + mb * HID;
            acc = b_bbox[mb];
            oidx = NUM_PROP_AFTER * NUM_CLS + (sbase + s) * 2 * NUM_CLS + mb;
        }
        const float4* w4 = (const float4*)Wrow;
        for (int c = 0; c < 32; ++c) {
            uint4 hv = *(const uint4*)&hx[0][c][s][0];
            U32H2 p0, p1, p2, p3;
            p0.u = hv.x; p1.u = hv.y; p2.u = hv.z; p3.u = hv.w;
            float4 wa = w4[2 * c], wb = w4[2 * c + 1];
            acc += (float)p0.h[0] * wa.x + (float)p0.h[1] * wa.y +
                   (float)p1.h[0] * wa.z + (float)p1.h[1] * wa.w +
                   (float)p2.h[0] * wb.x + (float)p2.h[1] * wb.y +
                   (float)p3.h[0] * wb.z + (float)p3.h[1] * wb.w;
        }
        out[oidx] = acc;
    }
}

extern "C" void kernel_launch(void* const* d_in, const int* in_sizes, int n_in,
                              void* d_out, int out_size, void* d_ws,
                              size_t ws_size, hipStream_t stream) {
    const float* data = (const float*)d_in[0];     // [8192, 64]
    const float* prop = (const float*)d_in[1];     // [1024, 3]
    const float* W_ih = (const float*)d_in[2];     // [1024, 64]
    const float* W_hh = (const float*)d_in[3];     // [1024, 256]
    const float* b_ih = (const float*)d_in[4];     // [1024]
    const float* b_hh = (const float*)d_in[5];     // [1024]
    const float* W_cls = (const float*)d_in[6];    // [40, 256]
    const float* b_cls = (const float*)d_in[7];    // [40]
    const float* W_bbox = (const float*)d_in[8];   // [80, 256]
    const float* b_bbox = (const float*)d_in[9];   // [80]
    float* out = (float*)d_out;

    int* t0s = (int*)d_ws;                                       // 1 KB
    unsigned short* WQ = (unsigned short*)((char*)d_ws + 1024);  // 640 KB f16

    pack_w<<<1280, 256, 0, stream>>>(W_ih, W_hh, WQ);
    nms_kernel<<<1, 1024, 0, stream>>>(prop, t0s);
    lstm_kernel<<<NBLK, 512, 0, stream>>>(data, t0s, WQ, b_ih, b_hh, W_cls,
                                          b_cls, W_bbox, b_bbox, out);
}